// Round 13
// baseline (103.802 us; speedup 1.0000x reference)
//
#include <hip/hip_runtime.h>
#include <math.h>

#define BB 32
#define LL 128
#define HH 512
#define MM 512
#define NM 544          // 32 x-matrices + 512 centroids
#define EPSF 1e-8f
#define CPLEN 10240     // 10 upper 32x32 tiles * 1024 floats (offdiag pre-scaled by sqrt2)
#define NCH 40          // k-chunks of 256 floats
#define R2C 1.41421356237309505f

typedef __attribute__((ext_vector_type(8))) short short8b;   // 8 bf16
typedef __attribute__((ext_vector_type(4))) float f32x4;
typedef __attribute__((ext_vector_type(16))) float f32x16;

// ---------------- ws layout (floats) ----------------
#define NWS_CP    0
#define NWS_PART  5570560
#define NWS_NSQ   6225920
#define NWS_HSIC  6226464
#define NWS_IDS   6242848

#define AS1(p) ((const __attribute__((address_space(1))) void*)(p))
#define AS3(p) ((__attribute__((address_space(3))) void*)(p))

__device__ __forceinline__ unsigned pack2(unsigned lo, unsigned hi) {
    return (lo >> 16) | (hi & 0xffff0000u);
}

// exact 3-plane bf16 split of 8 floats (c = p0+p1+p2 to ~2^-24 rel)
__device__ __forceinline__ void split3(const float4 lo, const float4 hi,
                                       uint4& p0, uint4& p1, uint4& p2) {
    float c[8] = {lo.x, lo.y, lo.z, lo.w, hi.x, hi.y, hi.z, hi.w};
    unsigned h[8], m[8], l[8];
#pragma unroll
    for (int i = 0; i < 8; ++i) {
        h[i] = __float_as_uint(c[i]) & 0xffff0000u;
        const float r1 = c[i] - __uint_as_float(h[i]);
        m[i] = __float_as_uint(r1) & 0xffff0000u;
        l[i] = __float_as_uint(r1 - __uint_as_float(m[i]));
    }
    p0 = make_uint4(pack2(h[0],h[1]), pack2(h[2],h[3]), pack2(h[4],h[5]), pack2(h[6],h[7]));
    p1 = make_uint4(pack2(m[0],m[1]), pack2(m[2],m[3]), pack2(m[4],m[5]), pack2(m[6],m[7]));
    p2 = make_uint4(pack2(l[0],l[1]), pack2(l[2],l[3]), pack2(l[4],l[5]), pack2(l[6],l[7]));
}

// 6 significant plane-products: hh, hm, mh, mm, hl, lh
__device__ __forceinline__ void mfma6(f32x16& d, const short8b a[3], const short8b b[3]) {
    d = __builtin_amdgcn_mfma_f32_32x32x16_bf16(a[0], b[0], d, 0, 0, 0);
    d = __builtin_amdgcn_mfma_f32_32x32x16_bf16(a[0], b[1], d, 0, 0, 0);
    d = __builtin_amdgcn_mfma_f32_32x32x16_bf16(a[1], b[0], d, 0, 0, 0);
    d = __builtin_amdgcn_mfma_f32_32x32x16_bf16(a[1], b[1], d, 0, 0, 0);
    d = __builtin_amdgcn_mfma_f32_32x32x16_bf16(a[0], b[2], d, 0, 0, 0);
    d = __builtin_amdgcn_mfma_f32_32x32x16_bf16(a[2], b[0], d, 0, 0, 0);
}

// flat index of G[a][b] inside a 32x32 tile (verified 32x32 C/D layout:
// col=lane&31, row=(reg&3)+8*(reg>>2)+4*(lane>>5)); reg-quad c stored at
// (c*2+hi)*128 + col*4 + q.
__device__ __forceinline__ int flatAB(int a, int b) {
    return ((a >> 3) * 2 + ((a >> 2) & 1)) * 128 + b * 4 + (a & 3);
}
// upper-tile slot for i<=j: (0,0)=0,(0,1)=1,(0,2)=2,(0,3)=3,(1,1)=4,...
__device__ __forceinline__ int Tix(int i, int j) {
    return i * (7 - i) / 2 + j;
}

// write or accumulate one 32x32 tile into LDS buf
__device__ __forceinline__ void put_tile(float* buf, int slot, const f32x16& a,
                                         int lane, bool add) {
    const int hi = lane >> 5, col = lane & 31;
#pragma unroll
    for (int c = 0; c < 4; ++c) {
        const int idx = slot * 1024 + (c * 2 + hi) * 128 + col * 4;
        f32x4 v;
        v[0] = a[c * 4 + 0]; v[1] = a[c * 4 + 1];
        v[2] = a[c * 4 + 2]; v[3] = a[c * 4 + 3];
        if (add) {
            const f32x4 o = *(const f32x4*)&buf[idx];
            v[0] += o[0]; v[1] += o[1]; v[2] += o[2]; v[3] += o[3];
        }
        *(f32x4*)&buf[idx] = v;
    }
}

// =====================================================================
// Per-wave free-running worker. Wave owns NS strips over one k-half
// (256 k), staging k16 steps into its PRIVATE LDS slice via
// global_load_lds (double-buffered), per-wave counted vmcnt, NO
// barriers. Source granules permuted (l&3)^((l>>3)&3) so fragment
// ds_reads are 2-way bank-clean with matching read-side XOR.
// NS==2: tiles (S0,S0),(S0,S1),(S1,S1).  NS==3: tiles (S0,S1),(S0,S2).
// =====================================================================
template<int NS, int S0, int S1, int S2>
__device__ __forceinline__ void wave_main(const float* __restrict__ Amat,
                                          char* slice, int khalf, int lane,
                                          f32x16& t0, f32x16& t1, f32x16& t2)
{
    const int gsrc  = (lane & 3) ^ ((lane >> 3) & 3);
    const int rowin = lane >> 2;          // row within a 16-row DMA instr
    const int SS[3] = {S0, S1, S2};

    const float* srcb[NS][2];
#pragma unroll
    for (int s = 0; s < NS; ++s)
#pragma unroll
        for (int ih = 0; ih < 2; ++ih)
            srcb[s][ih] = Amat + (size_t)(SS[s] * 32 + ih * 16 + rowin) * HH
                          + khalf * 256 + gsrc * 4;

    // issue step 0 into pb=0
#pragma unroll
    for (int s = 0; s < NS; ++s)
#pragma unroll
        for (int ih = 0; ih < 2; ++ih)
            __builtin_amdgcn_global_load_lds(AS1(srcb[s][ih]),
                AS3(slice + s * 4096 + ih * 1024), 16, 0, 0);

    const int r31 = lane & 31;
    const int oct = lane >> 5;
    const int sw  = (r31 >> 1) & 3;
    const int off0 = ((2 * oct) ^ sw) << 4;
    const int off1 = ((2 * oct + 1) ^ sw) << 4;

#pragma unroll 2
    for (int t = 0; t < 16; ++t) {
        const int pb = t & 1;
        if (t < 15) {
#pragma unroll
            for (int s = 0; s < NS; ++s)
#pragma unroll
                for (int ih = 0; ih < 2; ++ih)
                    __builtin_amdgcn_global_load_lds(
                        AS1(srcb[s][ih] + (t + 1) * 16),
                        AS3(slice + s * 4096 + (pb ^ 1) * 2048 + ih * 1024),
                        16, 0, 0);
            if constexpr (NS == 2)
                asm volatile("s_waitcnt vmcnt(4)" ::: "memory");
            else
                asm volatile("s_waitcnt vmcnt(6)" ::: "memory");
        } else {
            asm volatile("s_waitcnt vmcnt(0)" ::: "memory");
        }
        short8b fr[3][3];
#pragma unroll
        for (int s = 0; s < NS; ++s) {
            const char* rp = slice + s * 4096 + pb * 2048 + r31 * 64;
            const float4 lo = *(const float4*)(rp + off0);
            const float4 hi = *(const float4*)(rp + off1);
            uint4 q0, q1, q2;
            split3(lo, hi, q0, q1, q2);
            fr[s][0] = *(short8b*)&q0;
            fr[s][1] = *(short8b*)&q1;
            fr[s][2] = *(short8b*)&q2;
        }
        if constexpr (NS == 2) {
            mfma6(t0, fr[0], fr[0]);
            mfma6(t1, fr[0], fr[1]);
            mfma6(t2, fr[1], fr[1]);
        } else {
            mfma6(t0, fr[0], fr[1]);
            mfma6(t1, fr[0], fr[2]);
        }
    }
}

// =====================================================================
// K1: free-running-wave centered Gram. 544 blocks x 512 threads (8
// waves, 1 block/CU). Wave wid: k-half wid>>2, group wid&3:
//  g0: strips{0,1} tiles (0,0),(0,1),(1,1) -> slots 0,1,4
//  g1: strips{2,3} tiles (2,2),(2,3),(3,3) -> slots 7,8,9
//  g2: strips{0,2,3} tiles (0,2),(0,3)     -> slots 2,3
//  g3: strips{1,2,3} tiles (1,2),(1,3)     -> slots 5,6
// Epilogue: 3 barriers; combine halves in LDS buf; R8-verified
// row-sums + double-centering + sqrt2-scaled upper-triangle store.
// =====================================================================
__global__ __launch_bounds__(512, 1)
void gram_free(const float* __restrict__ x,
               const float* __restrict__ cent,
               float* __restrict__ Cp,
               float* __restrict__ normsq)
{
    __shared__ __align__(16) char smem[81920];   // staging slices / buf union
    __shared__ float rmv[128];
    __shared__ float red[512];
    __shared__ float gmsh;

    const int tid = threadIdx.x, lane = tid & 63, wid = tid >> 6;
    const int n = blockIdx.x;
    const float* Amat = (n < BB) ? (x + (size_t)n * LL * HH)
                                 : (cent + (size_t)(n - BB) * LL * HH);

    const int khalf = wid >> 2;
    const int g     = wid & 3;
    char* slice = smem + khalf * 40960 + g * 8192 + (g == 3 ? 4096 : 0);

    f32x16 t0, t1, t2;
#pragma unroll
    for (int q = 0; q < 16; ++q) { t0[q] = 0.f; t1[q] = 0.f; t2[q] = 0.f; }

    switch (g) {
        case 0:  wave_main<2, 0, 1, 0>(Amat, slice, khalf, lane, t0, t1, t2); break;
        case 1:  wave_main<2, 2, 3, 0>(Amat, slice, khalf, lane, t0, t1, t2); break;
        case 2:  wave_main<3, 0, 2, 3>(Amat, slice, khalf, lane, t0, t1, t2); break;
        default: wave_main<3, 1, 2, 3>(Amat, slice, khalf, lane, t0, t1, t2); break;
    }

    __syncthreads();                    // all staging reads done
    float* buf = (float*)smem;          // 40 KB tile buffer (aliases slices)
    if (wid < 4) {
        if (g == 0)      { put_tile(buf, 0, t0, lane, false); put_tile(buf, 1, t1, lane, false); put_tile(buf, 4, t2, lane, false); }
        else if (g == 1) { put_tile(buf, 7, t0, lane, false); put_tile(buf, 8, t1, lane, false); put_tile(buf, 9, t2, lane, false); }
        else if (g == 2) { put_tile(buf, 2, t0, lane, false); put_tile(buf, 3, t1, lane, false); }
        else             { put_tile(buf, 5, t0, lane, false); put_tile(buf, 6, t1, lane, false); }
    }
    __syncthreads();
    if (wid >= 4) {
        if (g == 0)      { put_tile(buf, 0, t0, lane, true); put_tile(buf, 1, t1, lane, true); put_tile(buf, 4, t2, lane, true); }
        else if (g == 1) { put_tile(buf, 7, t0, lane, true); put_tile(buf, 8, t1, lane, true); put_tile(buf, 9, t2, lane, true); }
        else if (g == 2) { put_tile(buf, 2, t0, lane, true); put_tile(buf, 3, t1, lane, true); }
        else             { put_tile(buf, 5, t0, lane, true); put_tile(buf, 6, t1, lane, true); }
    }
    __syncthreads();

    // ---- row sums of raw G (for double-centering) ----
    float Sv = 0.f;
    if (tid < 128) {
        const int i = tid >> 5, ri = tid & 31;
#pragma unroll
        for (int j = 0; j < 4; ++j) {
            if (j >= i) {
                const int gt = Tix(i, j);
#pragma unroll
                for (int b = 0; b < 32; ++b)
                    Sv += buf[gt * 1024 + flatAB(ri, b)];
            } else {
                const int gt = Tix(j, i);
#pragma unroll
                for (int a = 0; a < 32; ++a)
                    Sv += buf[gt * 1024 + flatAB(a, ri)];
            }
        }
        rmv[tid] = Sv * (1.f / 128.f);
    }
    red[tid] = (tid < 128) ? Sv : 0.f;
    __syncthreads();
    for (int s2 = 256; s2 > 0; s2 >>= 1) {
        if (tid < s2) red[tid] += red[tid + s2];
        __syncthreads();
    }
    if (tid == 0) gmsh = red[0] * (1.f / 16384.f);
    __syncthreads();
    const float gm = gmsh;

    // ---- center + sqrt2-scale offdiag + store + ||C||^2 ----
    float nsq = 0.f;
    float* dstn = Cp + (size_t)n * CPLEN;
#pragma unroll
    for (int u5 = 0; u5 < 5; ++u5) {
        const int u  = u5 * 512 + tid;        // f32x4 index 0..2559
        const int gt = u >> 8;                // tile slot 0..9
        const int fo = (u & 255) * 4;         // float offset in tile
        const int c2 = fo >> 7;
        const int col = (fo >> 2) & 31;
        const int ar = (c2 >> 1) * 8 + (c2 & 1) * 4;
        int i, j;
        if (gt < 4)      { i = 0; j = gt; }
        else if (gt < 7) { i = 1; j = gt - 3; }
        else if (gt < 9) { i = 2; j = gt - 5; }
        else             { i = 3; j = 3; }
        const float sc = (i == j) ? 1.f : R2C;
        const f32x4 vv = *(const f32x4*)&buf[u * 4];
        const float cj = rmv[j * 32 + col];
        f32x4 o;
#pragma unroll
        for (int q = 0; q < 4; ++q) {
            const float val = (vv[q] + gm - rmv[i * 32 + ar + q] - cj) * sc;
            nsq = fmaf(val, val, nsq);
            o[q] = val;
        }
        *(f32x4*)(dstn + u * 4) = o;
    }
    __syncthreads();
    red[tid] = nsq;
    __syncthreads();
    for (int s2 = 256; s2 > 0; s2 >>= 1) {
        if (tid < s2) red[tid] += red[tid + s2];
        __syncthreads();
    }
    if (tid == 0) normsq[n] = red[0];
}

// =====================================================================
// K2: hsic partials. grid = 16 m-tiles x 40 k-chunks (640 blocks).
// =====================================================================
__global__ __launch_bounds__(256, 2)
void hsic_partial(const float* __restrict__ Cp, float* __restrict__ part)
{
    __shared__ float cx[32][260];
    __shared__ float red2[256][16];

    const int tid = threadIdx.x;
    const int bx  = blockIdx.x;
    const int mt  = bx / NCH;
    const int kc  = bx % NCH;
    const int k0  = kc * 256;

#pragma unroll
    for (int i = 0; i < 8; ++i) {
        const int idx = i * 1024 + tid * 4;
        const int b = idx >> 8, k = idx & 255;
        *(float4*)&cx[b][k] = *(const float4*)&Cp[(size_t)b * CPLEN + k0 + k];
    }
    __syncthreads();

    const int kq = tid >> 6;
    const int bg = (tid >> 3) & 7;
    const int mg = tid & 7;
    const float* cyBase = Cp + (size_t)(BB + mt * 32 + mg * 4) * CPLEN + k0 + kq * 64;

    float a[4][4];
#pragma unroll
    for (int bi = 0; bi < 4; ++bi)
#pragma unroll
        for (int mi = 0; mi < 4; ++mi) a[bi][mi] = 0.f;

    for (int kk = 0; kk < 16; ++kk) {
        float4 cy[4];
#pragma unroll
        for (int mi = 0; mi < 4; ++mi)
            cy[mi] = *(const float4*)(cyBase + (size_t)mi * CPLEN + kk * 4);
        float4 cxv[4];
#pragma unroll
        for (int bi = 0; bi < 4; ++bi)
            cxv[bi] = *(const float4*)&cx[bg + bi * 8][kq * 64 + kk * 4];
#pragma unroll
        for (int bi = 0; bi < 4; ++bi)
#pragma unroll
            for (int mi = 0; mi < 4; ++mi) {
                a[bi][mi] = fmaf(cxv[bi].x, cy[mi].x, a[bi][mi]);
                a[bi][mi] = fmaf(cxv[bi].y, cy[mi].y, a[bi][mi]);
                a[bi][mi] = fmaf(cxv[bi].z, cy[mi].z, a[bi][mi]);
                a[bi][mi] = fmaf(cxv[bi].w, cy[mi].w, a[bi][mi]);
            }
    }

#pragma unroll
    for (int e = 0; e < 16; ++e) red2[tid][e] = a[e >> 2][e & 3];
    __syncthreads();
    if (tid < 64) {
#pragma unroll
        for (int e = 0; e < 16; ++e) {
            const float s = red2[tid][e] + red2[tid + 64][e] +
                            red2[tid + 128][e] + red2[tid + 192][e];
            const int bi = e >> 2, mi = e & 3;
            const int b = ((tid >> 3) & 7) + bi * 8;
            const int m = mt * 32 + (tid & 7) * 4 + mi;
            part[((size_t)kc * 32 + b) * 512 + m] = s;
        }
    }
}

// =====================================================================
// K3: combine partials, loss matrix + per-row argmax (first occurrence)
// =====================================================================
__global__ __launch_bounds__(256)
void combine_loss(const float* __restrict__ part,
                  const float* __restrict__ normsq,
                  float* __restrict__ hsic,
                  int* __restrict__ ids,
                  float* __restrict__ out)
{
    __shared__ float rv[256];
    __shared__ int   ri[256];
    const int b = blockIdx.x;
    const int tid = threadIdx.x;
    const float vx = sqrtf(normsq[b]);

    float best = -INFINITY; int bm = 0;
    for (int m = tid; m < MM; m += 256) {
        float s = 0.f;
        for (int kc = 0; kc < NCH; ++kc)
            s += part[((size_t)kc * 32 + b) * 512 + m];
        hsic[b * MM + m] = s;
        const float vy = sqrtf(normsq[BB + m]);
        const float loss = -logf(fabsf(s) / (vx * vy) + EPSF);
        out[1 + b * MM + m] = loss;
        if (loss > best) { best = loss; bm = m; }   // ascending m keeps earliest
    }
    rv[tid] = best; ri[tid] = bm;
    __syncthreads();
    for (int s2 = 128; s2 > 0; s2 >>= 1) {
        if (tid < s2) {
            if (rv[tid + s2] > rv[tid] ||
                (rv[tid + s2] == rv[tid] && ri[tid + s2] < ri[tid])) {
                rv[tid] = rv[tid + s2]; ri[tid] = ri[tid + s2];
            }
        }
        __syncthreads();
    }
    if (tid == 0) { ids[b] = ri[0]; out[1 + BB * MM + b] = (float)ri[0]; }
}

// =====================================================================
// K4: scalar loss via gather identity hsic2[b,c] = hsic[b, idx[c]]
// =====================================================================
__global__ __launch_bounds__(1024)
void scalar_loss(const float* __restrict__ hsic,
                 const float* __restrict__ normsq,
                 const int* __restrict__ ids,
                 float* __restrict__ out)
{
    __shared__ float red[1024];
    const int tid = threadIdx.x;
    const int b = tid >> 5, c = tid & 31;
    const int m = ids[c];
    red[tid] = fabsf(hsic[b * MM + m]) /
               (sqrtf(normsq[b]) * sqrtf(normsq[BB + m]));
    __syncthreads();
    for (int s = 512; s > 0; s >>= 1) {
        if (tid < s) red[tid] += red[tid + s];
        __syncthreads();
    }
    if (tid == 0) out[0] = -logf(red[0] * (1.f / 1024.f) + EPSF);
}

// =====================================================================
extern "C" void kernel_launch(void* const* d_in, const int* in_sizes, int n_in,
                              void* d_out, int out_size, void* d_ws, size_t ws_size,
                              hipStream_t stream) {
    const float* x    = (const float*)d_in[0];   // (32,128,512)
    const float* cent = (const float*)d_in[1];   // (512, 128*512)
    float* out = (float*)d_out;
    float* ws  = (float*)d_ws;

    float* Cp     = ws + NWS_CP;
    float* part   = ws + NWS_PART;
    float* normsq = ws + NWS_NSQ;
    float* hsic   = ws + NWS_HSIC;
    int*   ids    = (int*)(ws + NWS_IDS);

    gram_free<<<NM, 512, 0, stream>>>(x, cent, Cp, normsq);
    hsic_partial<<<16 * NCH, 256, 0, stream>>>(Cp, part);
    combine_loss<<<BB, 256, 0, stream>>>(part, normsq, hsic, ids, out);
    scalar_loss<<<1, 1024, 0, stream>>>(hsic, normsq, ids, out);
}